// Round 1
// baseline (155.488 us; speedup 1.0000x reference)
//
#include <hip/hip_runtime.h>

#define NTOK 16384
#define NC 2048
#define C4 512            // float4 per row
#define NE 8
#define TPB 256
#define TOK_PER_BLOCK 32
#define NBLK (NTOK / TOK_PER_BLOCK)   // 512

__global__ void zero_ws_kernel(float* ws) {
    if (threadIdx.x < 2 * NE) ws[threadIdx.x] = 0.0f;
}

__global__ __launch_bounds__(TPB, 2) void router_kernel(
    const float* __restrict__ x, const float* __restrict__ gw,
    float* __restrict__ out, float* __restrict__ ws) {
    __shared__ float4 s_gw[NE * C4];   // 64 KB
    __shared__ float s_psum[NE];
    __shared__ float s_cnt[NE];

    const int tid = threadIdx.x;
    if (tid < NE) { s_psum[tid] = 0.0f; s_cnt[tid] = 0.0f; }

    // stage gate_w -> LDS (4096 float4, 16 per thread, coalesced)
    const float4* gw4 = (const float4*)gw;
    #pragma unroll
    for (int i = tid; i < NE * C4; i += TPB) s_gw[i] = gw4[i];
    __syncthreads();

    const int wave = tid >> 6;
    const int lane = tid & 63;
    const float4* x4 = (const float4*)x;
    const int tok_base = blockIdx.x * TOK_PER_BLOCK;

    float* out_w = out;               // weights [N,2]
    float* out_i = out + 2 * NTOK;    // indices [N,2] stored as float

    for (int pass = 0; pass < 2; ++pass) {
        const int t0 = tok_base + wave * 8 + pass * 4;   // 4 tokens
        float acc[4][NE];
        #pragma unroll
        for (int t = 0; t < 4; ++t)
            #pragma unroll
            for (int e = 0; e < NE; ++e) acc[t][e] = 0.0f;

        #pragma unroll
        for (int k = 0; k < 8; ++k) {
            const int idx = lane + k * 64;
            float4 xv[4];
            #pragma unroll
            for (int t = 0; t < 4; ++t)
                xv[t] = x4[(size_t)(t0 + t) * C4 + idx];
            #pragma unroll
            for (int e = 0; e < NE; ++e) {
                const float4 wv = s_gw[e * C4 + idx];
                #pragma unroll
                for (int t = 0; t < 4; ++t) {
                    acc[t][e] += xv[t].x * wv.x + xv[t].y * wv.y +
                                 xv[t].z * wv.z + xv[t].w * wv.w;
                }
            }
        }

        // butterfly reduce over 64 lanes: every lane ends with full sums
        #pragma unroll
        for (int off = 32; off >= 1; off >>= 1) {
            #pragma unroll
            for (int t = 0; t < 4; ++t)
                #pragma unroll
                for (int e = 0; e < NE; ++e)
                    acc[t][e] += __shfl_xor(acc[t][e], off, 64);
        }

        if (lane < 4) {
            const int t = lane;
            const int token = t0 + t;
            float l[NE];
            #pragma unroll
            for (int e = 0; e < NE; ++e) l[e] = acc[t][e];

            float m = l[0];
            #pragma unroll
            for (int e = 1; e < NE; ++e) m = fmaxf(m, l[e]);
            float p[NE];
            float s = 0.0f;
            #pragma unroll
            for (int e = 0; e < NE; ++e) { p[e] = expf(l[e] - m); s += p[e]; }
            const float inv = 1.0f / s;
            #pragma unroll
            for (int e = 0; e < NE; ++e) p[e] *= inv;

            // top-2 with ties -> lower index (matches jax.lax.top_k)
            int i0 = 0; float p0 = p[0];
            #pragma unroll
            for (int e = 1; e < NE; ++e) if (p[e] > p0) { p0 = p[e]; i0 = e; }
            int i1 = (i0 == 0) ? 1 : 0; float p1 = p[i1];
            #pragma unroll
            for (int e = 0; e < NE; ++e)
                if (e != i0 && p[e] > p1) { p1 = p[e]; i1 = e; }

            const float wsum = p0 + p1;
            out_w[2 * token]     = p0 / wsum;
            out_w[2 * token + 1] = p1 / wsum;
            out_i[2 * token]     = (float)i0;
            out_i[2 * token + 1] = (float)i1;

            #pragma unroll
            for (int e = 0; e < NE; ++e) atomicAdd(&s_psum[e], p[e]);
            atomicAdd(&s_cnt[i0], 1.0f);
            atomicAdd(&s_cnt[i1], 1.0f);
        }
    }

    __syncthreads();
    if (tid < NE) {
        atomicAdd(&ws[tid], s_psum[tid]);
        atomicAdd(&ws[NE + tid], s_cnt[tid]);
    }
}

__global__ void finalize_kernel(const float* __restrict__ ws,
                                float* __restrict__ out) {
    float aux = 0.0f;
    #pragma unroll
    for (int e = 0; e < NE; ++e)
        aux += (ws[NE + e] * (1.0f / NTOK)) * (ws[e] * (1.0f / NTOK));
    out[4 * NTOK] = (float)NE * aux;
}

extern "C" void kernel_launch(void* const* d_in, const int* in_sizes, int n_in,
                              void* d_out, int out_size, void* d_ws, size_t ws_size,
                              hipStream_t stream) {
    const float* x  = (const float*)d_in[0];   // [4,4096,2048] f32
    const float* gw = (const float*)d_in[1];   // [8,2048] f32
    float* out = (float*)d_out;                // weights[N,2] | indices[N,2] | aux
    float* ws  = (float*)d_ws;                 // psum[8] | cnt[8]

    zero_ws_kernel<<<1, 64, 0, stream>>>(ws);
    router_kernel<<<NBLK, TPB, 0, stream>>>(x, gw, out, ws);
    finalize_kernel<<<1, 1, 0, stream>>>(ws, out);
}